// Round 8
// baseline (205.620 us; speedup 1.0000x reference)
//
#include <hip/hip_runtime.h>

#define N_H 8192
#define RANK 8
#define BATCH 2048
#define CPR (N_H / 4)      // 2048 float4 chunks per row
#define BLK 512
#define RB 2               // rows per block
#define ITER (CPR / BLK)   // 4 chunks per thread per row
#define NW (BLK / 64)      // 8 waves

// ---------------- Kernel T: Ut[r][n] = U[n][r] * (0.01/8192)
__global__ __launch_bounds__(256) void rnn_transpose_u(
    const float* __restrict__ U, float* __restrict__ Ut)
{
    constexpr float SCALE = 0.01f / (float)N_H;
    const int i = blockIdx.x * 256 + threadIdx.x;   // [0, RANK*N_H)
    const int r = i >> 13;
    const int n = i & (N_H - 1);
    Ut[i] = U[(size_t)n * RANK + r] * SCALE;
}

__device__ __forceinline__ float fast_tanh(float x) {
    float e = __expf(2.0f * x);
    return 1.0f - 2.0f / (e + 1.0f);
}

// ---------------- Fused: phase1 (P = tanh(h)·V^T) + phase3 (epilogue)
__global__ __launch_bounds__(BLK, 8) void rnn_fused(
    const float* __restrict__ ff, const float* __restrict__ h,
    const float* __restrict__ Ut, const float* __restrict__ V,
    float* __restrict__ out)
{
    const int t = threadIdx.x;
    const int lane = t & 63;
    const int wave = t >> 6;
    const int b0 = blockIdx.x * RB;
    const float4* __restrict__ H4 = (const float4*)h;
    const float4* __restrict__ V4 = (const float4*)V;   // [RANK][CPR]
    const float4* __restrict__ W4 = (const float4*)Ut;  // [RANK][CPR], prescaled
    const float4* __restrict__ FF4 = (const float4*)ff;
    float4* __restrict__ O4 = (float4*)out;

    // ---- Phase 1: per-thread partials (16 accumulators, k = j*RANK + r)
    float acc[RB * RANK];
    #pragma unroll
    for (int k = 0; k < RB * RANK; ++k) acc[k] = 0.0f;

    #pragma unroll
    for (int i = 0; i < ITER; ++i) {
        const int c = i * BLK + t;
        float4 hc[RB];
        #pragma unroll
        for (int j = 0; j < RB; ++j) hc[j] = H4[(size_t)(b0 + j) * CPR + c];
        // V group A (r=0..3) — loads issue while tanh computes
        float4 vA[4];
        #pragma unroll
        for (int r = 0; r < 4; ++r) vA[r] = V4[r * CPR + c];
        float th[RB][4];
        #pragma unroll
        for (int j = 0; j < RB; ++j) {
            th[j][0] = fast_tanh(hc[j].x); th[j][1] = fast_tanh(hc[j].y);
            th[j][2] = fast_tanh(hc[j].z); th[j][3] = fast_tanh(hc[j].w);
        }
        float4 vB[4];
        #pragma unroll
        for (int r = 0; r < 4; ++r) vB[r] = V4[(r + 4) * CPR + c];
        #pragma unroll
        for (int j = 0; j < RB; ++j)
            #pragma unroll
            for (int r = 0; r < 4; ++r)
                acc[j * RANK + r] += th[j][0] * vA[r].x + th[j][1] * vA[r].y
                                   + th[j][2] * vA[r].z + th[j][3] * vA[r].w;
        #pragma unroll
        for (int j = 0; j < RB; ++j)
            #pragma unroll
            for (int r = 0; r < 4; ++r)
                acc[j * RANK + r + 4] += th[j][0] * vB[r].x + th[j][1] * vB[r].y
                                       + th[j][2] * vB[r].z + th[j][3] * vB[r].w;
    }

    // ---- packed wave reduction: 16 values -> lane l holds S_{l&15}
    float v8[8];
    {
        const bool hi = (lane & 1);
        #pragma unroll
        for (int m = 0; m < 8; ++m) {
            float a = acc[2 * m], b = acc[2 * m + 1];
            float keep = hi ? b : a;
            float send = hi ? a : b;
            v8[m] = keep + __shfl_xor(send, 1, 64);
        }
    }
    float v4r[4];
    {
        const bool hi = (lane & 2);
        #pragma unroll
        for (int m = 0; m < 4; ++m) {
            float a = v8[2 * m], b = v8[2 * m + 1];
            float keep = hi ? b : a;
            float send = hi ? a : b;
            v4r[m] = keep + __shfl_xor(send, 2, 64);
        }
    }
    float v2r[2];
    {
        const bool hi = (lane & 4);
        #pragma unroll
        for (int m = 0; m < 2; ++m) {
            float a = v4r[2 * m], b = v4r[2 * m + 1];
            float keep = hi ? b : a;
            float send = hi ? a : b;
            v2r[m] = keep + __shfl_xor(send, 4, 64);
        }
    }
    float v1;
    {
        const bool hi = (lane & 8);
        float a = v2r[0], b = v2r[1];
        float keep = hi ? b : a;
        float send = hi ? a : b;
        v1 = keep + __shfl_xor(send, 8, 64);
    }
    v1 += __shfl_xor(v1, 16, 64);
    v1 += __shfl_xor(v1, 32, 64);   // lane l holds S_{l&15}

    // ---- cross-wave combine -> Pp[16]
    __shared__ float red[NW][16];
    __shared__ float Pp[RB * RANK];
    if (lane < 16) red[wave][lane] = v1;
    __syncthreads();
    if (t < RB * RANK) {
        float s = 0.0f;
        #pragma unroll
        for (int w = 0; w < NW; ++w) s += red[w][t];
        Pp[t] = s;
    }
    __syncthreads();

    // block-uniform -> SGPRs (frees 16 VGPRs; v_fmac with SGPR src0 is legal)
    float p[RB][RANK];
    #pragma unroll
    for (int j = 0; j < RB; ++j)
        #pragma unroll
        for (int r = 0; r < RANK; ++r)
            p[j][r] = __builtin_amdgcn_readfirstlane(Pp[j * RANK + r]);

    // ---- Phase 3: out = 0.99*h + 0.01*ff + sum_r p*Ut  (h re-read is L2-hot)
    constexpr float CA = 1.0f - 0.01f;
    constexpr float CB = 0.01f;

    #pragma unroll
    for (int i = 0; i < ITER; ++i) {
        const int c = i * BLK + t;
        float4 f4 = FF4[c];
        float4 wA[4];
        #pragma unroll
        for (int r = 0; r < 4; ++r) wA[r] = W4[r * CPR + c];
        float4 wB[4];
        #pragma unroll
        for (int r = 0; r < 4; ++r) wB[r] = W4[(r + 4) * CPR + c];
        #pragma unroll
        for (int j = 0; j < RB; ++j) {
            float4 h4 = H4[(size_t)(b0 + j) * CPR + c];
            float4 o;
            o.x = CA * h4.x + CB * f4.x;
            o.y = CA * h4.y + CB * f4.y;
            o.z = CA * h4.z + CB * f4.z;
            o.w = CA * h4.w + CB * f4.w;
            #pragma unroll
            for (int r = 0; r < 4; ++r) {
                o.x += p[j][r] * wA[r].x;
                o.y += p[j][r] * wA[r].y;
                o.z += p[j][r] * wA[r].z;
                o.w += p[j][r] * wA[r].w;
            }
            #pragma unroll
            for (int r = 0; r < 4; ++r) {
                o.x += p[j][r + 4] * wB[r].x;
                o.y += p[j][r + 4] * wB[r].y;
                o.z += p[j][r + 4] * wB[r].z;
                o.w += p[j][r + 4] * wB[r].w;
            }
            O4[(size_t)(b0 + j) * CPR + c] = o;
        }
    }
}

extern "C" void kernel_launch(void* const* d_in, const int* in_sizes, int n_in,
                              void* d_out, int out_size, void* d_ws, size_t ws_size,
                              hipStream_t stream) {
    const float* ff = (const float*)d_in[0];   // [8192]
    const float* h  = (const float*)d_in[1];   // [2048, 8192]
    const float* U  = (const float*)d_in[2];   // [8192, 8]
    const float* V  = (const float*)d_in[3];   // [8, 8192]
    float* out = (float*)d_out;                // [2048, 8192]
    float* Ut  = (float*)d_ws;                 // [RANK][N_H] = 256 KB

    rnn_transpose_u<<<dim3((RANK * N_H) / 256), dim3(256), 0, stream>>>(U, Ut);
    rnn_fused<<<dim3(BATCH / RB), dim3(BLK), 0, stream>>>(ff, h, Ut, V, out);
}

// Round 9
// 149.324 us; speedup vs baseline: 1.3770x; 1.3770x over previous
//
#include <hip/hip_runtime.h>

#define N_H 8192
#define RANK 8
#define BATCH 2048
#define CPR (N_H / 4)      // 2048 float4 chunks per row
#define BLK 512
#define RB 2               // rows per block
#define ITER (CPR / BLK)   // 4 chunks per thread per row
#define NW (BLK / 64)      // 8 waves

// ---------------- Kernel T: Ut[r][n] = U[n][r] * (0.01/8192)
__global__ __launch_bounds__(256) void rnn_transpose_u(
    const float* __restrict__ U, float* __restrict__ Ut)
{
    constexpr float SCALE = 0.01f / (float)N_H;
    const int i = blockIdx.x * 256 + threadIdx.x;   // [0, RANK*N_H)
    const int r = i >> 13;
    const int n = i & (N_H - 1);
    Ut[i] = U[(size_t)n * RANK + r] * SCALE;
}

__device__ __forceinline__ float fast_tanh(float x) {
    float e = __expf(2.0f * x);
    return 1.0f - 2.0f / (e + 1.0f);
}

// ---------------- Fused: phase1 (P = tanh(h)·V^T) + phase3 (epilogue)
// launch_bounds(512,4): ~64 VGPR budget — round 8's (512,8) forced 32 and spilled
// (WRITE_SIZE 192 MB = out + spills). Keep 1024-block grid for occupancy.
__global__ __launch_bounds__(BLK, 4) void rnn_fused(
    const float* __restrict__ ff, const float* __restrict__ h,
    const float* __restrict__ Ut, const float* __restrict__ V,
    float* __restrict__ out)
{
    const int t = threadIdx.x;
    const int lane = t & 63;
    const int wave = t >> 6;
    const int b0 = blockIdx.x * RB;
    const float4* __restrict__ H4 = (const float4*)h;
    const float4* __restrict__ V4 = (const float4*)V;   // [RANK][CPR]
    const float4* __restrict__ W4 = (const float4*)Ut;  // [RANK][CPR], prescaled
    const float4* __restrict__ FF4 = (const float4*)ff;
    float4* __restrict__ O4 = (float4*)out;

    // ---- Phase 1: per-thread partials (16 accumulators, k = j*RANK + r)
    float acc[RB * RANK];
    #pragma unroll
    for (int k = 0; k < RB * RANK; ++k) acc[k] = 0.0f;

    #pragma unroll
    for (int i = 0; i < ITER; ++i) {
        const int c = i * BLK + t;
        float4 hc[RB];
        #pragma unroll
        for (int j = 0; j < RB; ++j) hc[j] = H4[(size_t)(b0 + j) * CPR + c];
        // V group A (r=0..3) — loads issue while tanh computes
        float4 vA[4];
        #pragma unroll
        for (int r = 0; r < 4; ++r) vA[r] = V4[r * CPR + c];
        float th[RB][4];
        #pragma unroll
        for (int j = 0; j < RB; ++j) {
            th[j][0] = fast_tanh(hc[j].x); th[j][1] = fast_tanh(hc[j].y);
            th[j][2] = fast_tanh(hc[j].z); th[j][3] = fast_tanh(hc[j].w);
        }
        float4 vB[4];
        #pragma unroll
        for (int r = 0; r < 4; ++r) vB[r] = V4[(r + 4) * CPR + c];
        #pragma unroll
        for (int j = 0; j < RB; ++j)
            #pragma unroll
            for (int r = 0; r < 4; ++r)
                acc[j * RANK + r] += th[j][0] * vA[r].x + th[j][1] * vA[r].y
                                   + th[j][2] * vA[r].z + th[j][3] * vA[r].w;
        #pragma unroll
        for (int j = 0; j < RB; ++j)
            #pragma unroll
            for (int r = 0; r < 4; ++r)
                acc[j * RANK + r + 4] += th[j][0] * vB[r].x + th[j][1] * vB[r].y
                                       + th[j][2] * vB[r].z + th[j][3] * vB[r].w;
    }

    // ---- packed wave reduction: 16 values -> lane l holds S_{l&15}
    float v8[8];
    {
        const bool hi = (lane & 1);
        #pragma unroll
        for (int m = 0; m < 8; ++m) {
            float a = acc[2 * m], b = acc[2 * m + 1];
            float keep = hi ? b : a;
            float send = hi ? a : b;
            v8[m] = keep + __shfl_xor(send, 1, 64);
        }
    }
    float v4r[4];
    {
        const bool hi = (lane & 2);
        #pragma unroll
        for (int m = 0; m < 4; ++m) {
            float a = v8[2 * m], b = v8[2 * m + 1];
            float keep = hi ? b : a;
            float send = hi ? a : b;
            v4r[m] = keep + __shfl_xor(send, 2, 64);
        }
    }
    float v2r[2];
    {
        const bool hi = (lane & 4);
        #pragma unroll
        for (int m = 0; m < 2; ++m) {
            float a = v4r[2 * m], b = v4r[2 * m + 1];
            float keep = hi ? b : a;
            float send = hi ? a : b;
            v2r[m] = keep + __shfl_xor(send, 4, 64);
        }
    }
    float v1;
    {
        const bool hi = (lane & 8);
        float a = v2r[0], b = v2r[1];
        float keep = hi ? b : a;
        float send = hi ? a : b;
        v1 = keep + __shfl_xor(send, 8, 64);
    }
    v1 += __shfl_xor(v1, 16, 64);
    v1 += __shfl_xor(v1, 32, 64);   // lane l holds S_{l&15}

    // ---- cross-wave combine -> Pp[16]
    __shared__ float red[NW][16];
    __shared__ float Pp[RB * RANK];
    if (lane < 16) red[wave][lane] = v1;
    __syncthreads();
    if (t < RB * RANK) {
        float s = 0.0f;
        #pragma unroll
        for (int w = 0; w < NW; ++w) s += red[w][t];
        Pp[t] = s;
    }
    __syncthreads();

    // block-uniform -> SGPRs (frees 16 VGPRs)
    float p[RB][RANK];
    #pragma unroll
    for (int j = 0; j < RB; ++j)
        #pragma unroll
        for (int r = 0; r < RANK; ++r)
            p[j][r] = __builtin_amdgcn_readfirstlane(Pp[j * RANK + r]);

    // ---- Phase 3: out = 0.99*h + 0.01*ff + sum_r p*Ut  (h re-read is L2-hot)
    constexpr float CA = 1.0f - 0.01f;
    constexpr float CB = 0.01f;

    #pragma unroll
    for (int i = 0; i < ITER; ++i) {
        const int c = i * BLK + t;
        float4 f4 = FF4[c];
        float4 wA[4];
        #pragma unroll
        for (int r = 0; r < 4; ++r) wA[r] = W4[r * CPR + c];
        float4 wB[4];
        #pragma unroll
        for (int r = 0; r < 4; ++r) wB[r] = W4[(r + 4) * CPR + c];
        #pragma unroll
        for (int j = 0; j < RB; ++j) {
            float4 h4 = H4[(size_t)(b0 + j) * CPR + c];
            float4 o;
            o.x = CA * h4.x + CB * f4.x;
            o.y = CA * h4.y + CB * f4.y;
            o.z = CA * h4.z + CB * f4.z;
            o.w = CA * h4.w + CB * f4.w;
            #pragma unroll
            for (int r = 0; r < 4; ++r) {
                o.x += p[j][r] * wA[r].x;
                o.y += p[j][r] * wA[r].y;
                o.z += p[j][r] * wA[r].z;
                o.w += p[j][r] * wA[r].w;
            }
            #pragma unroll
            for (int r = 0; r < 4; ++r) {
                o.x += p[j][r + 4] * wB[r].x;
                o.y += p[j][r + 4] * wB[r].y;
                o.z += p[j][r + 4] * wB[r].z;
                o.w += p[j][r + 4] * wB[r].w;
            }
            O4[(size_t)(b0 + j) * CPR + c] = o;
        }
    }
}

extern "C" void kernel_launch(void* const* d_in, const int* in_sizes, int n_in,
                              void* d_out, int out_size, void* d_ws, size_t ws_size,
                              hipStream_t stream) {
    const float* ff = (const float*)d_in[0];   // [8192]
    const float* h  = (const float*)d_in[1];   // [2048, 8192]
    const float* U  = (const float*)d_in[2];   // [8192, 8]
    const float* V  = (const float*)d_in[3];   // [8, 8192]
    float* out = (float*)d_out;                // [2048, 8192]
    float* Ut  = (float*)d_ws;                 // [RANK][N_H] = 256 KB

    rnn_transpose_u<<<dim3((RANK * N_H) / 256), dim3(256), 0, stream>>>(U, Ut);
    rnn_fused<<<dim3(BATCH / RB), dim3(BLK), 0, stream>>>(ff, h, Ut, V, out);
}

// Round 10
// 142.357 us; speedup vs baseline: 1.4444x; 1.0489x over previous
//
#include <hip/hip_runtime.h>

#define N_H 8192
#define RANK 8
#define BATCH 2048
#define CPR (N_H / 4)      // 2048 float4 chunks per row
#define BLK 512
#define RB 4               // rows per block (round 7 config — best measured)
#define ITER (CPR / BLK)   // 4 chunks per thread per row
#define NW (BLK / 64)      // 8 waves

// ---------------- Kernel T: Ut[r][n] = U[n][r] * (0.01/8192)
__global__ __launch_bounds__(256) void rnn_transpose_u(
    const float* __restrict__ U, float* __restrict__ Ut)
{
    constexpr float SCALE = 0.01f / (float)N_H;
    const int i = blockIdx.x * 256 + threadIdx.x;   // [0, RANK*N_H)
    const int r = i >> 13;
    const int n = i & (N_H - 1);
    Ut[i] = U[(size_t)n * RANK + r] * SCALE;
}

__device__ __forceinline__ float fast_tanh(float x) {
    float e = __expf(2.0f * x);
    return 1.0f - 2.0f / (e + 1.0f);
}

// ---------------- Fused: phase1 (P = tanh(h)·V^T) + phase3 (epilogue)
// Change vs round 7: per-block column-walk stagger (off) to break L2 hot-line
// contention — all blocks otherwise request the SAME V/Ut cache lines in
// lockstep, serializing on a few L2 slices. off is 64-chunk aligned so wave
// coalescing is preserved; & (CPR-1) wrap is exact (2048 chunks).
__global__ __launch_bounds__(BLK, 4) void rnn_fused(
    const float* __restrict__ ff, const float* __restrict__ h,
    const float* __restrict__ Ut, const float* __restrict__ V,
    float* __restrict__ out)
{
    const int t = threadIdx.x;
    const int lane = t & 63;
    const int wave = t >> 6;
    const int b0 = blockIdx.x * RB;
    const int off = ((blockIdx.x * 5) & 31) * 64;    // 32 offsets, 4 KB apart
    const float4* __restrict__ H4 = (const float4*)h;
    const float4* __restrict__ V4 = (const float4*)V;   // [RANK][CPR]
    const float4* __restrict__ W4 = (const float4*)Ut;  // [RANK][CPR], prescaled
    const float4* __restrict__ FF4 = (const float4*)ff;
    float4* __restrict__ O4 = (float4*)out;

    // ---- Phase 1: per-thread partials over full rows
    float v32[RB * RANK];
    #pragma unroll
    for (int k = 0; k < RB * RANK; ++k) v32[k] = 0.0f;

    float4 hc[RB];
    {
        const int c0 = (t + off) & (CPR - 1);
        #pragma unroll
        for (int j = 0; j < RB; ++j) hc[j] = H4[(size_t)(b0 + j) * CPR + c0];
    }

    #pragma unroll
    for (int i = 0; i < ITER; ++i) {
        const int c = (i * BLK + t + off) & (CPR - 1);
        float4 v4[RANK];
        #pragma unroll
        for (int r = 0; r < RANK; ++r) v4[r] = V4[r * CPR + c];
        float4 hn[RB];
        if (i + 1 < ITER) {              // prefetch next h chunk (HBM latency)
            const int cn = ((i + 1) * BLK + t + off) & (CPR - 1);
            #pragma unroll
            for (int j = 0; j < RB; ++j)
                hn[j] = H4[(size_t)(b0 + j) * CPR + cn];
        }
        #pragma unroll
        for (int j = 0; j < RB; ++j) {
            float tx = fast_tanh(hc[j].x), ty = fast_tanh(hc[j].y);
            float tz = fast_tanh(hc[j].z), tw = fast_tanh(hc[j].w);
            #pragma unroll
            for (int r = 0; r < RANK; ++r)
                v32[j * RANK + r] += tx * v4[r].x + ty * v4[r].y
                                   + tz * v4[r].z + tw * v4[r].w;
        }
        if (i + 1 < ITER) {
            #pragma unroll
            for (int j = 0; j < RB; ++j) hc[j] = hn[j];
        }
    }

    // ---- packed wave reduction: 32 values -> lane l holds S_{l&31}
    float v16[16];
    {
        const bool hi = (lane & 1);
        #pragma unroll
        for (int m = 0; m < 16; ++m) {
            float a = v32[2 * m], b = v32[2 * m + 1];
            float keep = hi ? b : a;
            float send = hi ? a : b;
            v16[m] = keep + __shfl_xor(send, 1, 64);
        }
    }
    float v8[8];
    {
        const bool hi = (lane & 2);
        #pragma unroll
        for (int m = 0; m < 8; ++m) {
            float a = v16[2 * m], b = v16[2 * m + 1];
            float keep = hi ? b : a;
            float send = hi ? a : b;
            v8[m] = keep + __shfl_xor(send, 2, 64);
        }
    }
    float v4r[4];
    {
        const bool hi = (lane & 4);
        #pragma unroll
        for (int m = 0; m < 4; ++m) {
            float a = v8[2 * m], b = v8[2 * m + 1];
            float keep = hi ? b : a;
            float send = hi ? a : b;
            v4r[m] = keep + __shfl_xor(send, 4, 64);
        }
    }
    float v2r[2];
    {
        const bool hi = (lane & 8);
        #pragma unroll
        for (int m = 0; m < 2; ++m) {
            float a = v4r[2 * m], b = v4r[2 * m + 1];
            float keep = hi ? b : a;
            float send = hi ? a : b;
            v2r[m] = keep + __shfl_xor(send, 8, 64);
        }
    }
    float v1;
    {
        const bool hi = (lane & 16);
        float a = v2r[0], b = v2r[1];
        float keep = hi ? b : a;
        float send = hi ? a : b;
        v1 = keep + __shfl_xor(send, 16, 64);
    }
    v1 += __shfl_xor(v1, 32, 64);   // lane l (l<32) holds S_{l&31}

    // ---- cross-wave combine -> Pp[32] in LDS
    __shared__ float red[NW][32];
    __shared__ float Pp[RB * RANK];
    if (lane < 32) red[wave][lane] = v1;
    __syncthreads();
    if (t < 32) {
        float s = 0.0f;
        #pragma unroll
        for (int w = 0; w < NW; ++w) s += red[w][t];
        Pp[t] = s;   // index k = j*RANK + r
    }
    __syncthreads();

    float p[RB][RANK];
    #pragma unroll
    for (int j = 0; j < RB; ++j)
        #pragma unroll
        for (int r = 0; r < RANK; ++r) p[j][r] = Pp[j * RANK + r];  // broadcast

    // ---- Phase 3: out = 0.99*h + 0.01*ff + sum_r p*Ut  (h re-read L2/L3-hot)
    constexpr float CA = 1.0f - 0.01f;
    constexpr float CB = 0.01f;

    #pragma unroll
    for (int i = 0; i < ITER; ++i) {
        const int c = (i * BLK + t + off) & (CPR - 1);
        float4 f4 = FF4[c];
        float4 w[RANK];
        #pragma unroll
        for (int r = 0; r < RANK; ++r) w[r] = W4[r * CPR + c];
        #pragma unroll
        for (int j = 0; j < RB; ++j) {
            float4 h4 = H4[(size_t)(b0 + j) * CPR + c];
            float4 o;
            o.x = CA * h4.x + CB * f4.x;
            o.y = CA * h4.y + CB * f4.y;
            o.z = CA * h4.z + CB * f4.z;
            o.w = CA * h4.w + CB * f4.w;
            #pragma unroll
            for (int r = 0; r < RANK; ++r) {
                o.x += p[j][r] * w[r].x;
                o.y += p[j][r] * w[r].y;
                o.z += p[j][r] * w[r].z;
                o.w += p[j][r] * w[r].w;
            }
            O4[(size_t)(b0 + j) * CPR + c] = o;
        }
    }
}

extern "C" void kernel_launch(void* const* d_in, const int* in_sizes, int n_in,
                              void* d_out, int out_size, void* d_ws, size_t ws_size,
                              hipStream_t stream) {
    const float* ff = (const float*)d_in[0];   // [8192]
    const float* h  = (const float*)d_in[1];   // [2048, 8192]
    const float* U  = (const float*)d_in[2];   // [8192, 8]
    const float* V  = (const float*)d_in[3];   // [8, 8192]
    float* out = (float*)d_out;                // [2048, 8192]
    float* Ut  = (float*)d_ws;                 // [RANK][N_H] = 256 KB

    rnn_transpose_u<<<dim3((RANK * N_H) / 256), dim3(256), 0, stream>>>(U, Ut);
    rnn_fused<<<dim3(BATCH / RB), dim3(BLK), 0, stream>>>(ff, h, Ut, V, out);
}

// Round 11
// 141.360 us; speedup vs baseline: 1.4546x; 1.0071x over previous
//
#include <hip/hip_runtime.h>

#define N_H 8192
#define RANK 8
#define BATCH 2048
#define CPR (N_H / 4)      // 2048 float4 chunks per row
#define BLK 512
#define RB 4               // rows per block
#define ITER (CPR / BLK)   // 4 chunks per thread per row
#define NW (BLK / 64)      // 8 waves

// ---------------- Kernel T: Ut[r][n] = U[n][r] * (0.01/8192)
__global__ __launch_bounds__(256) void rnn_transpose_u(
    const float* __restrict__ U, float* __restrict__ Ut)
{
    constexpr float SCALE = 0.01f / (float)N_H;
    const int i = blockIdx.x * 256 + threadIdx.x;   // [0, RANK*N_H)
    const int r = i >> 13;
    const int n = i & (N_H - 1);
    Ut[i] = U[(size_t)n * RANK + r] * SCALE;
}

__device__ __forceinline__ float fast_tanh(float x) {
    float e = __expf(2.0f * x);
    return 1.0f - 2.0f / (e + 1.0f);
}

// ---------------- Phase 1: P[b][r] = sum_n tanh(h[b,n]) * V[r,n]
// Full rows (SEG=1), RB=4, 512 blocks. Pure HBM-read stream + L2 V.
__global__ __launch_bounds__(BLK, 4) void rnn_p1(
    const float* __restrict__ h, const float* __restrict__ V,
    float* __restrict__ P)
{
    const int t = threadIdx.x;
    const int lane = t & 63;
    const int wave = t >> 6;
    const int b0 = blockIdx.x * RB;
    const float4* __restrict__ H4 = (const float4*)h;
    const float4* __restrict__ V4 = (const float4*)V;   // [RANK][CPR]

    float v32[RB * RANK];
    #pragma unroll
    for (int k = 0; k < RB * RANK; ++k) v32[k] = 0.0f;

    float4 hc[RB];
    #pragma unroll
    for (int j = 0; j < RB; ++j) hc[j] = H4[(size_t)(b0 + j) * CPR + t];

    #pragma unroll
    for (int i = 0; i < ITER; ++i) {
        const int c = i * BLK + t;
        float4 v4[RANK];
        #pragma unroll
        for (int r = 0; r < RANK; ++r) v4[r] = V4[r * CPR + c];
        float4 hn[RB];
        if (i + 1 < ITER) {              // prefetch next h chunk
            #pragma unroll
            for (int j = 0; j < RB; ++j)
                hn[j] = H4[(size_t)(b0 + j) * CPR + c + BLK];
        }
        #pragma unroll
        for (int j = 0; j < RB; ++j) {
            float tx = fast_tanh(hc[j].x), ty = fast_tanh(hc[j].y);
            float tz = fast_tanh(hc[j].z), tw = fast_tanh(hc[j].w);
            #pragma unroll
            for (int r = 0; r < RANK; ++r)
                v32[j * RANK + r] += tx * v4[r].x + ty * v4[r].y
                                   + tz * v4[r].z + tw * v4[r].w;
        }
        if (i + 1 < ITER) {
            #pragma unroll
            for (int j = 0; j < RB; ++j) hc[j] = hn[j];
        }
    }

    // packed wave reduction: 32 values -> lane l holds S_{l&31}
    float v16[16];
    {
        const bool hi = (lane & 1);
        #pragma unroll
        for (int m = 0; m < 16; ++m) {
            float a = v32[2 * m], b = v32[2 * m + 1];
            float keep = hi ? b : a, send = hi ? a : b;
            v16[m] = keep + __shfl_xor(send, 1, 64);
        }
    }
    float v8[8];
    {
        const bool hi = (lane & 2);
        #pragma unroll
        for (int m = 0; m < 8; ++m) {
            float a = v16[2 * m], b = v16[2 * m + 1];
            float keep = hi ? b : a, send = hi ? a : b;
            v8[m] = keep + __shfl_xor(send, 2, 64);
        }
    }
    float v4r[4];
    {
        const bool hi = (lane & 4);
        #pragma unroll
        for (int m = 0; m < 4; ++m) {
            float a = v8[2 * m], b = v8[2 * m + 1];
            float keep = hi ? b : a, send = hi ? a : b;
            v4r[m] = keep + __shfl_xor(send, 4, 64);
        }
    }
    float v2r[2];
    {
        const bool hi = (lane & 8);
        #pragma unroll
        for (int m = 0; m < 2; ++m) {
            float a = v4r[2 * m], b = v4r[2 * m + 1];
            float keep = hi ? b : a, send = hi ? a : b;
            v2r[m] = keep + __shfl_xor(send, 8, 64);
        }
    }
    float v1;
    {
        const bool hi = (lane & 16);
        float a = v2r[0], b = v2r[1];
        float keep = hi ? b : a, send = hi ? a : b;
        v1 = keep + __shfl_xor(send, 16, 64);
    }
    v1 += __shfl_xor(v1, 32, 64);   // lane l (l<32) holds S_{l&31}

    __shared__ float red[NW][32];
    if (lane < 32) red[wave][lane] = v1;
    __syncthreads();
    if (t < 32) {
        float s = 0.0f;
        #pragma unroll
        for (int w = 0; w < NW; ++w) s += red[w][t];
        P[(size_t)(b0 + (t >> 3)) * RANK + (t & 7)] = s;  // k = j*RANK + r
    }
}

// ---------------- Phase 2: out = 0.99*h + 0.01*ff + sum_r p[b][r]*Ut[r][n]
// h re-read should be L3-resident (just streamed); out is the HBM write stream.
__global__ __launch_bounds__(BLK, 4) void rnn_p2(
    const float* __restrict__ ff, const float* __restrict__ h,
    const float* __restrict__ Ut, const float* __restrict__ P,
    float* __restrict__ out)
{
    const int t = threadIdx.x;
    const int b0 = blockIdx.x * RB;
    const float4* __restrict__ H4 = (const float4*)h;
    const float4* __restrict__ W4 = (const float4*)Ut;  // [RANK][CPR], prescaled
    const float4* __restrict__ FF4 = (const float4*)ff;
    float4* __restrict__ O4 = (float4*)out;

    constexpr float CA = 1.0f - 0.01f;
    constexpr float CB = 0.01f;

    // wave-uniform -> scalar loads; Ut carries the 0.01/8192 scale
    float p[RB][RANK];
    #pragma unroll
    for (int j = 0; j < RB; ++j)
        #pragma unroll
        for (int r = 0; r < RANK; ++r)
            p[j][r] = P[(size_t)(b0 + j) * RANK + r];

    #pragma unroll
    for (int i = 0; i < ITER; ++i) {
        const int c = i * BLK + t;
        float4 f4 = FF4[c];
        float4 w[RANK];
        #pragma unroll
        for (int r = 0; r < RANK; ++r) w[r] = W4[r * CPR + c];
        #pragma unroll
        for (int j = 0; j < RB; ++j) {
            float4 h4 = H4[(size_t)(b0 + j) * CPR + c];
            float4 o;
            o.x = CA * h4.x + CB * f4.x;
            o.y = CA * h4.y + CB * f4.y;
            o.z = CA * h4.z + CB * f4.z;
            o.w = CA * h4.w + CB * f4.w;
            #pragma unroll
            for (int r = 0; r < RANK; ++r) {
                o.x += p[j][r] * w[r].x;
                o.y += p[j][r] * w[r].y;
                o.z += p[j][r] * w[r].z;
                o.w += p[j][r] * w[r].w;
            }
            O4[(size_t)(b0 + j) * CPR + c] = o;
        }
    }
}

extern "C" void kernel_launch(void* const* d_in, const int* in_sizes, int n_in,
                              void* d_out, int out_size, void* d_ws, size_t ws_size,
                              hipStream_t stream) {
    const float* ff = (const float*)d_in[0];   // [8192]
    const float* h  = (const float*)d_in[1];   // [2048, 8192]
    const float* U  = (const float*)d_in[2];   // [8192, 8]
    const float* V  = (const float*)d_in[3];   // [8, 8192]
    float* out = (float*)d_out;                // [2048, 8192]
    float* Ut  = (float*)d_ws;                 // [RANK][N_H] = 256 KB
    float* P   = (float*)((char*)d_ws + RANK * N_H * sizeof(float)); // [BATCH][RANK]

    rnn_transpose_u<<<dim3((RANK * N_H) / 256), dim3(256), 0, stream>>>(U, Ut);
    rnn_p1<<<dim3(BATCH / RB), dim3(BLK), 0, stream>>>(h, V, P);
    rnn_p2<<<dim3(BATCH / RB), dim3(BLK), 0, stream>>>(ff, h, Ut, P, out);
}